// Round 10
// baseline (3982.274 us; speedup 1.0000x reference)
//
#include <hip/hip_runtime.h>
#include <math.h>

// Dims (fixed by the problem)
#define BB 8
#define SS 512
#define DD 512
#define HH 8
#define HSD 64
#define FFD 2048
#define LL 6
#define VV 1024
#define NROWS (BB*SS)          // 4096
#define EPS 1e-5f

// ---------------------------------------------------------------------------
// Embed (unchanged — passing config)
// ---------------------------------------------------------------------------
__global__ __launch_bounds__(256)
void embed_kernel(const float* __restrict__ tokens,
                  const float* __restrict__ emb,
                  float* __restrict__ x)
{
    const int n = blockIdx.x;            // 0..4095
    const int s = n & (SS - 1);
    const int t = threadIdx.x;
    __shared__ int sidx;
    #pragma unroll
    for (int r = 0; r < 4; ++r) {
        int v = t + 256 * r;
        if (tokens[(long)n * VV + v] > 0.5f) sidx = v;
    }
    __syncthreads();
    const int idx = sidx;
    const float sq = 22.62741699796952f; // sqrt(512)
    #pragma unroll
    for (int r = 0; r < 2; ++r) {
        int d = t + 256 * r;
        float e = emb[(long)idx * DD + d] * sq;
        float expo  = (2.0f * (float)d) / 512.0f;
        float denom = powf(10000.0f, expo);
        float val   = (float)s / denom;
        float pe = ((d & 1) == 0) ? sinf(val) : cosf(val);
        x[(long)n * DD + d] = e + pe;
    }
}

// ---------------------------------------------------------------------------
// global->LDS DMA helper (width 16; dest = wave-uniform base + lane*16)
// ---------------------------------------------------------------------------
__device__ __forceinline__ void gll16(const float* g, float* l)
{
    __builtin_amdgcn_global_load_lds(
        (const __attribute__((address_space(1))) void*)g,
        (__attribute__((address_space(3))) void*)l, 16, 0, 0);
}

// ---------------------------------------------------------------------------
// Tiled GEMM — ROUND-7 configuration restored verbatim (best measured:
// BK=32, 16x16 thread grid, 8xNW micro-tile, GLL width-16 B-staging,
// SPLITK<=2). Round-9's 8x8 micro-tile regressed: LDS b128 throughput is
// ~85 B/cyc/CU (not 128), so 1.0 B/FMA is still LDS-bound, and the halved
// grids cut the TLP that was hiding the LDS stall. This structure is at its
// LDS-pipe ceiling (~48% of fp32 peak).
// QKVB: B is qkv_w [H][D][192]; global col c maps to head c/192, col c%192.
// ---------------------------------------------------------------------------
template<int TNB, bool BT, bool QKVB, bool BIAS, bool RELU, bool RES, int SPLITK>
__global__ __launch_bounds__(256)
void gemm_t(const float* __restrict__ A, const float* __restrict__ B,
            const float* __restrict__ bias, const float* __restrict__ res,
            float* __restrict__ C,
            int M, int N, int K, int lda, int ldb, int ldc)
{
    constexpr int NW   = TNB / 16;         // cols per thread
    constexpr int BSTR = BT ? (TNB + 4) : TNB;   // Bs row stride
    constexpr int CPW  = TNB / 32;         // GLL chunks per wave
    constexpr int CLOG = (TNB == 128) ? 7 : 6;   // log2(TNB)
    const int t  = threadIdx.x;
    const int w  = t >> 6;                 // wave 0..3
    const int ln = t & 63;
    const int bm = blockIdx.y * 128;
    const int bn = blockIdx.x * TNB;
    __shared__ float As[32][132];
    __shared__ __align__(16) float Bs[32][BSTR];
    const int tx = t & 15;                 // col group (tx*NW)
    const int ty = t >> 4;                 // row group (ty*8)
    float acc[8][NW] = {};

    const int kspan = K / SPLITK;
    const int kbase = (SPLITK > 1) ? blockIdx.z * kspan : 0;

    for (int k0 = kbase; k0 < kbase + kspan; k0 += 32) {
        if (QKVB || !BT) {                 // B: GLL DMA, linear row-major tile
            #pragma unroll
            for (int p = 0; p < CPW; ++p) {
                int ch = w * CPW + p;      // 1024B chunk id
                int fo = ch * 256 + ln * 4;        // float offset in 32xTNB tile
                int r  = fo >> CLOG;
                int c  = fo & (TNB - 1);
                const float* src;
                if (QKVB) {
                    int col = bn + c;
                    int hh = (int)((unsigned)col / 192u);
                    int j  = col - hh * 192;
                    src = B + (long)hh * (DD * 192) + (long)(k0 + r) * 192 + j;
                } else {
                    src = B + (long)(k0 + r) * ldb + bn + c;
                }
                gll16(src, &Bs[0][0] + ch * 256);
            }
        } else {
            #pragma unroll
            for (int p = 0; p < TNB / 32; ++p) {  // B^T: TNB rows x 32 k -> Bs[k][n]
                int q = t + 256 * p;
                int r = q >> 3, kc = (q & 7) * 4;
                float4 b4 = *(const float4*)(B + (long)(bn + r) * ldb + k0 + kc);
                Bs[kc + 0][r] = b4.x; Bs[kc + 1][r] = b4.y;
                Bs[kc + 2][r] = b4.z; Bs[kc + 3][r] = b4.w;
            }
        }
        #pragma unroll
        for (int p = 0; p < 4; ++p) {      // A: 128x32 -> As[k][m] transposed
            int q = t + 256 * p;           // 0..1023
            int r = q >> 3, kc = (q & 7) * 4;
            float4 a4 = *(const float4*)(A + (long)(bm + r) * lda + k0 + kc);
            As[kc + 0][r] = a4.x; As[kc + 1][r] = a4.y;
            As[kc + 2][r] = a4.z; As[kc + 3][r] = a4.w;
        }
        __syncthreads();
        #pragma unroll
        for (int kk = 0; kk < 32; ++kk) {
            float a[8], bv[NW];
            *(float4*)&a[0] = *(const float4*)&As[kk][ty * 8];
            *(float4*)&a[4] = *(const float4*)&As[kk][ty * 8 + 4];
            #pragma unroll
            for (int g = 0; g < NW / 4; ++g)
                *(float4*)&bv[g * 4] = *(const float4*)&Bs[kk][tx * NW + g * 4];
            #pragma unroll
            for (int ii = 0; ii < 8; ++ii)
                #pragma unroll
                for (int jj = 0; jj < NW; ++jj)
                    acc[ii][jj] += a[ii] * bv[jj];
        }
        __syncthreads();
    }

    float* Cp = (SPLITK > 1) ? (C + (long)blockIdx.z * ((long)M * ldc)) : C;
    #pragma unroll
    for (int ii = 0; ii < 8; ++ii) {
        int r = bm + ty * 8 + ii;
        #pragma unroll
        for (int jj = 0; jj < NW; ++jj) {
            int c = bn + tx * NW + jj;
            float v = acc[ii][jj];
            if (BIAS) v += bias[c];
            if (RELU) v = fmaxf(v, 0.0f);
            if (RES)  v += res[(long)r * ldc + c];
            Cp[(long)r * ldc + c] = v;
        }
    }
}

// ---------------------------------------------------------------------------
// Attention — round-7 version (causal tile skip, 180 µs, VGPR 96,
// 0 conflicts) + ONE addition: s_setprio(1) around the compute phases
// (dot chain / PV chain), (0) during staging. Measured precedent: m191
// (+4-7% attn when co-resident blocks are at different phases — here 2
// blocks/CU, one staging while one computes). No numerical effect.
// qkv layout: [n][h][192] (q:0..63,k:64..127,v:128..191), row stride 1536.
// ---------------------------------------------------------------------------
__global__ __launch_bounds__(256)
void attn_kernel(const float* __restrict__ qkv, float* __restrict__ oc)
{
    const int i0 = blockIdx.x * 16;
    const int h  = blockIdx.y, b = blockIdx.z;
    const int t  = threadIdx.x;
    const int w  = t >> 6;               // wave 0..3 -> rows 4w..4w+3
    const int ln = t & 63;               // lane -> j offset / output d

    __shared__ __align__(16) float Qs[16][64];     // Q rows (broadcast reads)
    __shared__ __align__(16) float KV[2][64 * 64]; // dbuf K (swz) / V (linear)
    __shared__ __align__(16) float Zb[16][512];    // z, then P (wave-local rows)

    const float* __restrict__ base = qkv + (long)b * SS * 1536 + (long)h * 192;

    const int rB = ln >> 4;              // row-within-quad 0..3
    const int g0 = ln & 15;              // 16B group within 64-float row
    const int gx = g0 ^ rB;              // precombined K-swizzle term

    const int kt_start = i0 >> 6;        // # fully-masked leading K-tiles

    // ---- initial stage: Q (1 GLL/wave) + K tile kt_start (4 GLL/wave) ----
    gll16(base + (long)(i0 + 4 * w + rB) * 1536 + g0 * 4, &Qs[4 * w][0]);
    #pragma unroll
    for (int p = 0; p < 4; ++p) {
        int q = 4 * w + p;               // 16-row sub-block 0..15
        int r = 4 * q + rB;              // tile row 0..63
        int g = (gx ^ (p << 2)) << 2;    // = (g0 ^ (r&15)) * 4 floats
        gll16(base + (long)(kt_start * 64 + r) * 1536 + 64 + g, &KV[0][q * 256]);
    }
    __syncthreads();

    // ---- fully-masked prefix: scores are exactly 0 (mask MULTIPLIES) ----
    for (int kt = 0; kt < kt_start; ++kt) {
        #pragma unroll
        for (int c = 0; c < 4; ++c)
            Zb[4 * w + c][kt * 64 + ln] = 0.0f;   // wave-local rows, no barrier
    }

    // ---- pass 1: scores over needed tiles (dot chain verbatim) ----
    for (int kt = kt_start; kt < 8; ++kt) {
        const int cur = (kt - kt_start) & 1;
        float* nb = &KV[cur ^ 1][0];
        if (kt < 7) {                    // prefetch next K tile (pre-swizzled src)
            const int j0n = (kt + 1) * 64;
            #pragma unroll
            for (int p = 0; p < 4; ++p) {
                int q = 4 * w + p;
                int r = 4 * q + rB;
                int g = (gx ^ (p << 2)) << 2;
                gll16(base + (long)(j0n + r) * 1536 + 64 + g, nb + q * 256);
            }
        } else {                         // prefetch V tile 0 (linear row-major)
            #pragma unroll
            for (int p = 0; p < 4; ++p) {
                int q = 4 * w + p;
                int r = 4 * q + rB;
                gll16(base + (long)r * 1536 + 128 + g0 * 4, nb + q * 256);
            }
        }

        const float* cb = &KV[cur][0];
        __builtin_amdgcn_s_setprio(1);   // favor compute waves on this CU
        float4 kreg[16];                 // K[j0+ln][0..63], 16B-group unswizzle
        #pragma unroll
        for (int kk = 0; kk < 16; ++kk)
            kreg[kk] = *(const float4*)(cb + ln * 64 + ((kk ^ g0) << 2));

        const int j0 = kt * 64;
        #pragma unroll
        for (int c = 0; c < 4; ++c) {
            const int i = 4 * w + c;
            const float4* q4 = (const float4*)&Qs[i][0];
            float dot = 0.0f;
            #pragma unroll
            for (int kk = 0; kk < 16; ++kk) {
                float4 kv = kreg[kk];
                float4 qq = q4[kk];
                dot += qq.x * kv.x + qq.y * kv.y + qq.z * kv.z + qq.w * kv.w;
            }
            const int gi = i0 + i, gj = j0 + ln;
            Zb[i][j0 + ln] = (gj <= gi) ? 0.0f : (dot * -1.0e6f) * 0.125f;
        }
        __builtin_amdgcn_s_setprio(0);
        __syncthreads();
    }

    // ---- softmax (each wave: its 4 rows; verbatim reductions; no barrier) ----
    #pragma unroll
    for (int c = 0; c < 4; ++c) {
        const int i = 4 * w + c;
        float p[8];
        float mx = -3.4e38f;
        #pragma unroll
        for (int r = 0; r < 8; ++r) { p[r] = Zb[i][r * 64 + ln]; mx = fmaxf(mx, p[r]); }
        #pragma unroll
        for (int o = 32; o >= 1; o >>= 1) mx = fmaxf(mx, __shfl_xor(mx, o));
        float sum = 0.0f;
        #pragma unroll
        for (int r = 0; r < 8; ++r) { p[r] = expf(p[r] - mx); sum += p[r]; }
        #pragma unroll
        for (int o = 32; o >= 1; o >>= 1) sum += __shfl_xor(sum, o);
        const float inv = 1.0f / sum;
        #pragma unroll
        for (int r = 0; r < 8; ++r) Zb[i][r * 64 + ln] = p[r] * inv;
    }

    // ---- pass 2: O = P V, sequential-j fmac chain (verbatim statements) ----
    // V tile 0 sits in KV[kt_start&1] (prefetched during pass-1 kt=7).
    float oA[4] = {0.0f, 0.0f, 0.0f, 0.0f};
    for (int kt = 0; kt < 8; ++kt) {
        const int cur = (kt + kt_start) & 1;
        if (kt < 7) {                    // prefetch next V tile (linear)
            float* nb = &KV[cur ^ 1][0];
            const int j0n = (kt + 1) * 64;
            #pragma unroll
            for (int p = 0; p < 4; ++p) {
                int q = 4 * w + p;
                int r = 4 * q + rB;
                gll16(base + (long)(j0n + r) * 1536 + 128 + g0 * 4, nb + q * 256);
            }
        }

        const float* cb = &KV[cur][0];
        __builtin_amdgcn_s_setprio(1);   // favor compute waves on this CU
        float vreg[64];                  // V[j0+kk][ln], column reads: 2-way free
        #pragma unroll
        for (int kk = 0; kk < 64; ++kk) vreg[kk] = cb[kk * 64 + ln];

        const int j0 = kt * 64;
        #pragma unroll
        for (int c = 0; c < 4; ++c) {
            const int i = 4 * w + c;
            const float4* pr = (const float4*)&Zb[i][j0];
            float acc = oA[c];
            #pragma unroll
            for (int kk = 0; kk < 16; ++kk) {
                float4 pv = pr[kk];
                acc += pv.x * vreg[kk * 4 + 0];
                acc += pv.y * vreg[kk * 4 + 1];
                acc += pv.z * vreg[kk * 4 + 2];
                acc += pv.w * vreg[kk * 4 + 3];
            }
            oA[c] = acc;
        }
        __builtin_amdgcn_s_setprio(0);
        if (kt < 7) __syncthreads();
    }

    // epilogue: concat-head layout oc[n][h*64 + d], d = lane (coalesced)
    #pragma unroll
    for (int c = 0; c < 4; ++c) {
        const int gi = i0 + 4 * w + c;
        oc[(long)(b * SS + gi) * DD + h * HSD + ln] = oA[c];
    }
}

// ---------------------------------------------------------------------------
// LayerNorm with fused split-K=2 reduction (round-5 version, unchanged).
// ---------------------------------------------------------------------------
__device__ __forceinline__ float blk_sum(float v, float* sb)
{
    #pragma unroll
    for (int m = 32; m >= 1; m >>= 1) v += __shfl_xor(v, m);
    if ((threadIdx.x & 63) == 0) sb[threadIdx.x >> 6] = v;
    __syncthreads();
    v = sb[0] + sb[1] + sb[2] + sb[3];
    __syncthreads();
    return v;
}

template<int NP>
__global__ __launch_bounds__(256)
void ln_fuse_kernel(const float* __restrict__ P, const float* __restrict__ bias,
                    const float* __restrict__ res,
                    const float* __restrict__ g, const float* __restrict__ bb,
                    float* __restrict__ out)
{
    __shared__ float sb[4];
    const int n = blockIdx.x;
    const int t = threadIdx.x;
    float v0 = P[(long)n * DD + t];
    float v1 = P[(long)n * DD + t + 256];
    #pragma unroll
    for (int p = 1; p < NP; ++p) {
        v0 += P[(long)p * NROWS * DD + (long)n * DD + t];
        v1 += P[(long)p * NROWS * DD + (long)n * DD + t + 256];
    }
    v0 += bias[t];       v1 += bias[t + 256];
    v0 += res[(long)n * DD + t];
    v1 += res[(long)n * DD + t + 256];

    float total = blk_sum(v0 + v1, sb);
    float mean = total * (1.0f / 512.0f);
    float d0 = v0 - mean, d1 = v1 - mean;
    float ss = blk_sum(d0 * d0 + d1 * d1, sb);
    float var = ss * (1.0f / 512.0f);
    float inv = 1.0f / sqrtf(var + EPS);
    out[(long)n * DD + t]       = d0 * inv * g[t]       + bb[t];
    out[(long)n * DD + t + 256] = d1 * inv * g[t + 256] + bb[t + 256];
}

// ---------------------------------------------------------------------------
extern "C" void kernel_launch(void* const* d_in, const int* in_sizes, int n_in,
                              void* d_out, int out_size, void* d_ws, size_t ws_size,
                              hipStream_t stream)
{
    const float* tokens = (const float*)d_in[0];
    const float* emb    = (const float*)d_in[1];
    const float* qkv_w  = (const float*)d_in[2];
    const float* qkv_b  = (const float*)d_in[3];
    const float* out_w  = (const float*)d_in[4];
    const float* out_b  = (const float*)d_in[5];
    const float* w1     = (const float*)d_in[6];
    const float* b1     = (const float*)d_in[7];
    const float* w2     = (const float*)d_in[8];
    const float* b2     = (const float*)d_in[9];
    const float* ln1_g  = (const float*)d_in[10];
    const float* ln1_b  = (const float*)d_in[11];
    const float* ln2_g  = (const float*)d_in[12];
    const float* ln2_b  = (const float*)d_in[13];
    float* out = (float*)d_out;

    float* ws  = (float*)d_ws;
    float* x   = ws;                          // [4096,512]
    float* y   = x  + (long)NROWS * DD;       // [4096,512]
    float* oc  = y  + (long)NROWS * DD;       // [4096,512]
    float* big = oc + (long)NROWS * DD;       // [4096,2048]
    // split-K=2 partial buffers (round-5 layout; zero extra workspace):
    //  - out-proj partials: big[0..2M), big[2M..4M)   (big free until FFN1)
    //  - FFN2 partials:     y[0..2M) and oc (contiguous after y)
    float* opP  = big;                        // 2 x [4096,512]
    float* ffP  = y;                          // slice 0; slice 1 = y + 2M = oc

    embed_kernel<<<NROWS, 256, 0, stream>>>(tokens, emb, x);

    for (int l = 0; l < LL; ++l) {
        const float* qw  = qkv_w + (long)l * HH * DD * 192;
        const float* qb  = qkv_b + (long)l * HH * 192;
        const float* ow  = out_w + (long)l * DD * DD;
        const float* ob  = out_b + (long)l * DD;
        const float* w1l = w1 + (long)l * DD * FFD;
        const float* b1l = b1 + (long)l * FFD;
        const float* w2l = w2 + (long)l * FFD * DD;
        const float* b2l = b2 + (long)l * DD;

        // QKV: [4096,512] @ per-head-remapped [512,1536] -> big (ldc=1536)
        gemm_t<64, false, true, true, false, false, 1><<<dim3(24, 32), 256, 0, stream>>>(
            x, qw, qb, nullptr, big, NROWS, 1536, DD, DD, 192, 1536);

        attn_kernel<<<dim3(SS / 16, HH, BB), 256, 0, stream>>>(big, oc);

        // out-proj, split-K=2 -> raw partials in big (free until FFN1)
        gemm_t<64, false, false, false, false, false, 2><<<dim3(8, 32, 2), 256, 0, stream>>>(
            oc, ow, nullptr, nullptr, opP, NROWS, DD, DD, DD, DD, DD);

        // ln1 fused: (p0+p1)+ob+x -> LN -> x
        ln_fuse_kernel<2><<<NROWS, 256, 0, stream>>>(
            opP, ob, x, ln1_g + (long)l * DD, ln1_b + (long)l * DD, x);

        // FFN1 + relu -> big
        gemm_t<128, false, false, true, true, false, 1><<<dim3(16, 32), 256, 0, stream>>>(
            x, w1l, b1l, nullptr, big, NROWS, FFD, DD, DD, FFD, FFD);

        // FFN2, split-K=2 -> raw partials in y/oc (both free here)
        gemm_t<64, false, false, false, false, false, 2><<<dim3(8, 32, 2), 256, 0, stream>>>(
            big, w2l, nullptr, nullptr, ffP, NROWS, DD, FFD, FFD, DD, DD);

        // ln2 fused: (p0+p1)+b2+x -> LN -> x
        ln_fuse_kernel<2><<<NROWS, 256, 0, stream>>>(
            ffP, b2l, x, ln2_g + (long)l * DD, ln2_b + (long)l * DD, x);
    }

    // final: out = x @ emb^T
    gemm_t<64, true, false, false, false, false, 1><<<dim3(16, 32), 256, 0, stream>>>(
        x, emb, nullptr, nullptr, out, NROWS, VV, DD, DD, DD, VV);
}

// Round 11
// 3133.818 us; speedup vs baseline: 1.2707x; 1.2707x over previous
//
#include <hip/hip_runtime.h>
#include <math.h>

// Dims (fixed by the problem)
#define BB 8
#define SS 512
#define DD 512
#define HH 8
#define HSD 64
#define FFD 2048
#define LL 6
#define VV 1024
#define NROWS (BB*SS)          // 4096
#define EPS 1e-5f

// ---------------------------------------------------------------------------
// Embed (unchanged — passing config)
// ---------------------------------------------------------------------------
__global__ __launch_bounds__(256)
void embed_kernel(const float* __restrict__ tokens,
                  const float* __restrict__ emb,
                  float* __restrict__ x)
{
    const int n = blockIdx.x;            // 0..4095
    const int s = n & (SS - 1);
    const int t = threadIdx.x;
    __shared__ int sidx;
    #pragma unroll
    for (int r = 0; r < 4; ++r) {
        int v = t + 256 * r;
        if (tokens[(long)n * VV + v] > 0.5f) sidx = v;
    }
    __syncthreads();
    const int idx = sidx;
    const float sq = 22.62741699796952f; // sqrt(512)
    #pragma unroll
    for (int r = 0; r < 2; ++r) {
        int d = t + 256 * r;
        float e = emb[(long)idx * DD + d] * sq;
        float expo  = (2.0f * (float)d) / 512.0f;
        float denom = powf(10000.0f, expo);
        float val   = (float)s / denom;
        float pe = ((d & 1) == 0) ? sinf(val) : cosf(val);
        x[(long)n * DD + d] = e + pe;
    }
}

// ---------------------------------------------------------------------------
// global->LDS DMA helper (width 16; dest = wave-uniform base + lane*16)
// ---------------------------------------------------------------------------
__device__ __forceinline__ void gll16(const float* g, float* l)
{
    __builtin_amdgcn_global_load_lds(
        (const __attribute__((address_space(1))) void*)g,
        (__attribute__((address_space(3))) void*)l, 16, 0, 0);
}

// ---------------------------------------------------------------------------
// Tiled GEMM — round-7 configuration (best measured: BK=32, 16x16 thread
// grid, 8xNW micro-tile, GLL width-16 B-staging, SPLITK<=2). At its
// LDS-pipe structural ceiling (~48% fp32 peak); 8x8 tile regressed (r9),
// BK=64/splitK=4 regressed (r6). PROTECTED.
// QKVB: B is qkv_w [H][D][192]; global col c maps to head c/192, col c%192.
// ---------------------------------------------------------------------------
template<int TNB, bool BT, bool QKVB, bool BIAS, bool RELU, bool RES, int SPLITK>
__global__ __launch_bounds__(256)
void gemm_t(const float* __restrict__ A, const float* __restrict__ B,
            const float* __restrict__ bias, const float* __restrict__ res,
            float* __restrict__ C,
            int M, int N, int K, int lda, int ldb, int ldc)
{
    constexpr int NW   = TNB / 16;         // cols per thread
    constexpr int BSTR = BT ? (TNB + 4) : TNB;   // Bs row stride
    constexpr int CPW  = TNB / 32;         // GLL chunks per wave
    constexpr int CLOG = (TNB == 128) ? 7 : 6;   // log2(TNB)
    const int t  = threadIdx.x;
    const int w  = t >> 6;                 // wave 0..3
    const int ln = t & 63;
    const int bm = blockIdx.y * 128;
    const int bn = blockIdx.x * TNB;
    __shared__ float As[32][132];
    __shared__ __align__(16) float Bs[32][BSTR];
    const int tx = t & 15;                 // col group (tx*NW)
    const int ty = t >> 4;                 // row group (ty*8)
    float acc[8][NW] = {};

    const int kspan = K / SPLITK;
    const int kbase = (SPLITK > 1) ? blockIdx.z * kspan : 0;

    for (int k0 = kbase; k0 < kbase + kspan; k0 += 32) {
        if (QKVB || !BT) {                 // B: GLL DMA, linear row-major tile
            #pragma unroll
            for (int p = 0; p < CPW; ++p) {
                int ch = w * CPW + p;      // 1024B chunk id
                int fo = ch * 256 + ln * 4;        // float offset in 32xTNB tile
                int r  = fo >> CLOG;
                int c  = fo & (TNB - 1);
                const float* src;
                if (QKVB) {
                    int col = bn + c;
                    int hh = (int)((unsigned)col / 192u);
                    int j  = col - hh * 192;
                    src = B + (long)hh * (DD * 192) + (long)(k0 + r) * 192 + j;
                } else {
                    src = B + (long)(k0 + r) * ldb + bn + c;
                }
                gll16(src, &Bs[0][0] + ch * 256);
            }
        } else {
            #pragma unroll
            for (int p = 0; p < TNB / 32; ++p) {  // B^T: TNB rows x 32 k -> Bs[k][n]
                int q = t + 256 * p;
                int r = q >> 3, kc = (q & 7) * 4;
                float4 b4 = *(const float4*)(B + (long)(bn + r) * ldb + k0 + kc);
                Bs[kc + 0][r] = b4.x; Bs[kc + 1][r] = b4.y;
                Bs[kc + 2][r] = b4.z; Bs[kc + 3][r] = b4.w;
            }
        }
        #pragma unroll
        for (int p = 0; p < 4; ++p) {      // A: 128x32 -> As[k][m] transposed
            int q = t + 256 * p;           // 0..1023
            int r = q >> 3, kc = (q & 7) * 4;
            float4 a4 = *(const float4*)(A + (long)(bm + r) * lda + k0 + kc);
            As[kc + 0][r] = a4.x; As[kc + 1][r] = a4.y;
            As[kc + 2][r] = a4.z; As[kc + 3][r] = a4.w;
        }
        __syncthreads();
        #pragma unroll
        for (int kk = 0; kk < 32; ++kk) {
            float a[8], bv[NW];
            *(float4*)&a[0] = *(const float4*)&As[kk][ty * 8];
            *(float4*)&a[4] = *(const float4*)&As[kk][ty * 8 + 4];
            #pragma unroll
            for (int g = 0; g < NW / 4; ++g)
                *(float4*)&bv[g * 4] = *(const float4*)&Bs[kk][tx * NW + g * 4];
            #pragma unroll
            for (int ii = 0; ii < 8; ++ii)
                #pragma unroll
                for (int jj = 0; jj < NW; ++jj)
                    acc[ii][jj] += a[ii] * bv[jj];
        }
        __syncthreads();
    }

    float* Cp = (SPLITK > 1) ? (C + (long)blockIdx.z * ((long)M * ldc)) : C;
    #pragma unroll
    for (int ii = 0; ii < 8; ++ii) {
        int r = bm + ty * 8 + ii;
        #pragma unroll
        for (int jj = 0; jj < NW; ++jj) {
            int c = bn + tx * NW + jj;
            float v = acc[ii][jj];
            if (BIAS) v += bias[c];
            if (RELU) v = fmaxf(v, 0.0f);
            if (RES)  v += res[(long)r * ldc + c];
            Cp[(long)r * ldc + c] = v;
        }
    }
}

// ---------------------------------------------------------------------------
// Attention — round-7 version (causal tile skip, 180 µs, VGPR 96, 0
// conflicts; setprio REVERTED — it inflated VGPR to 164 and halved
// residency, r10) + ONE new change: XCD-chunked block remap (T1).
// Linear block id round-robins across the 8 XCDs, so the 32 query-blocks
// sharing one (b,h) K/V panel were spread over 8 L2s (FETCH 67.7MB vs
// 24MB unique, ~2.8x re-fetch). Remap wl=(wid&7)*256+(wid>>3) gives XCD k
// exactly batch b=k: its whole qkv working set (3MB) fits the 4MB L2, so
// double-buffered prefetches become L2 hits (~200cy) instead of HBM
// (~900cy) and finish under the compute tile. Bijective (2048%8==0).
// Zero numerical change.
// qkv layout: [n][h][192] (q:0..63,k:64..127,v:128..191), row stride 1536.
// ---------------------------------------------------------------------------
__global__ __launch_bounds__(256)
void attn_kernel(const float* __restrict__ qkv, float* __restrict__ oc)
{
    // XCD-chunked remap of the 2048-block grid (32 q-blocks, 8 h, 8 b)
    const int wid = blockIdx.x + (SS / 16) * (blockIdx.y + HH * blockIdx.z);
    const int wl  = (wid & 7) * 256 + (wid >> 3);   // XCD k -> b=k chunk
    const int b   = wl >> 8;             // 0..7
    const int h   = (wl >> 5) & 7;       // 0..7
    const int i0  = (wl & 31) * 16;      // query-row block

    const int t  = threadIdx.x;
    const int w  = t >> 6;               // wave 0..3 -> rows 4w..4w+3
    const int ln = t & 63;               // lane -> j offset / output d

    __shared__ __align__(16) float Qs[16][64];     // Q rows (broadcast reads)
    __shared__ __align__(16) float KV[2][64 * 64]; // dbuf K (swz) / V (linear)
    __shared__ __align__(16) float Zb[16][512];    // z, then P (wave-local rows)

    const float* __restrict__ base = qkv + (long)b * SS * 1536 + (long)h * 192;

    const int rB = ln >> 4;              // row-within-quad 0..3
    const int g0 = ln & 15;              // 16B group within 64-float row
    const int gx = g0 ^ rB;              // precombined K-swizzle term

    const int kt_start = i0 >> 6;        // # fully-masked leading K-tiles

    // ---- initial stage: Q (1 GLL/wave) + K tile kt_start (4 GLL/wave) ----
    gll16(base + (long)(i0 + 4 * w + rB) * 1536 + g0 * 4, &Qs[4 * w][0]);
    #pragma unroll
    for (int p = 0; p < 4; ++p) {
        int q = 4 * w + p;               // 16-row sub-block 0..15
        int r = 4 * q + rB;              // tile row 0..63
        int g = (gx ^ (p << 2)) << 2;    // = (g0 ^ (r&15)) * 4 floats
        gll16(base + (long)(kt_start * 64 + r) * 1536 + 64 + g, &KV[0][q * 256]);
    }
    __syncthreads();

    // ---- fully-masked prefix: scores are exactly 0 (mask MULTIPLIES) ----
    for (int kt = 0; kt < kt_start; ++kt) {
        #pragma unroll
        for (int c = 0; c < 4; ++c)
            Zb[4 * w + c][kt * 64 + ln] = 0.0f;   // wave-local rows, no barrier
    }

    // ---- pass 1: scores over needed tiles (dot chain verbatim) ----
    for (int kt = kt_start; kt < 8; ++kt) {
        const int cur = (kt - kt_start) & 1;
        float* nb = &KV[cur ^ 1][0];
        if (kt < 7) {                    // prefetch next K tile (pre-swizzled src)
            const int j0n = (kt + 1) * 64;
            #pragma unroll
            for (int p = 0; p < 4; ++p) {
                int q = 4 * w + p;
                int r = 4 * q + rB;
                int g = (gx ^ (p << 2)) << 2;
                gll16(base + (long)(j0n + r) * 1536 + 64 + g, nb + q * 256);
            }
        } else {                         // prefetch V tile 0 (linear row-major)
            #pragma unroll
            for (int p = 0; p < 4; ++p) {
                int q = 4 * w + p;
                int r = 4 * q + rB;
                gll16(base + (long)r * 1536 + 128 + g0 * 4, nb + q * 256);
            }
        }

        const float* cb = &KV[cur][0];
        float4 kreg[16];                 // K[j0+ln][0..63], 16B-group unswizzle
        #pragma unroll
        for (int kk = 0; kk < 16; ++kk)
            kreg[kk] = *(const float4*)(cb + ln * 64 + ((kk ^ g0) << 2));

        const int j0 = kt * 64;
        #pragma unroll
        for (int c = 0; c < 4; ++c) {
            const int i = 4 * w + c;
            const float4* q4 = (const float4*)&Qs[i][0];
            float dot = 0.0f;
            #pragma unroll
            for (int kk = 0; kk < 16; ++kk) {
                float4 kv = kreg[kk];
                float4 qq = q4[kk];
                dot += qq.x * kv.x + qq.y * kv.y + qq.z * kv.z + qq.w * kv.w;
            }
            const int gi = i0 + i, gj = j0 + ln;
            Zb[i][j0 + ln] = (gj <= gi) ? 0.0f : (dot * -1.0e6f) * 0.125f;
        }
        __syncthreads();
    }

    // ---- softmax (each wave: its 4 rows; verbatim reductions; no barrier) ----
    #pragma unroll
    for (int c = 0; c < 4; ++c) {
        const int i = 4 * w + c;
        float p[8];
        float mx = -3.4e38f;
        #pragma unroll
        for (int r = 0; r < 8; ++r) { p[r] = Zb[i][r * 64 + ln]; mx = fmaxf(mx, p[r]); }
        #pragma unroll
        for (int o = 32; o >= 1; o >>= 1) mx = fmaxf(mx, __shfl_xor(mx, o));
        float sum = 0.0f;
        #pragma unroll
        for (int r = 0; r < 8; ++r) { p[r] = expf(p[r] - mx); sum += p[r]; }
        #pragma unroll
        for (int o = 32; o >= 1; o >>= 1) sum += __shfl_xor(sum, o);
        const float inv = 1.0f / sum;
        #pragma unroll
        for (int r = 0; r < 8; ++r) Zb[i][r * 64 + ln] = p[r] * inv;
    }

    // ---- pass 2: O = P V, sequential-j fmac chain (verbatim statements) ----
    // V tile 0 sits in KV[kt_start&1] (prefetched during pass-1 kt=7).
    float oA[4] = {0.0f, 0.0f, 0.0f, 0.0f};
    for (int kt = 0; kt < 8; ++kt) {
        const int cur = (kt + kt_start) & 1;
        if (kt < 7) {                    // prefetch next V tile (linear)
            float* nb = &KV[cur ^ 1][0];
            const int j0n = (kt + 1) * 64;
            #pragma unroll
            for (int p = 0; p < 4; ++p) {
                int q = 4 * w + p;
                int r = 4 * q + rB;
                gll16(base + (long)(j0n + r) * 1536 + 128 + g0 * 4, nb + q * 256);
            }
        }

        const float* cb = &KV[cur][0];
        float vreg[64];                  // V[j0+kk][ln], column reads: 2-way free
        #pragma unroll
        for (int kk = 0; kk < 64; ++kk) vreg[kk] = cb[kk * 64 + ln];

        const int j0 = kt * 64;
        #pragma unroll
        for (int c = 0; c < 4; ++c) {
            const int i = 4 * w + c;
            const float4* pr = (const float4*)&Zb[i][j0];
            float acc = oA[c];
            #pragma unroll
            for (int kk = 0; kk < 16; ++kk) {
                float4 pv = pr[kk];
                acc += pv.x * vreg[kk * 4 + 0];
                acc += pv.y * vreg[kk * 4 + 1];
                acc += pv.z * vreg[kk * 4 + 2];
                acc += pv.w * vreg[kk * 4 + 3];
            }
            oA[c] = acc;
        }
        if (kt < 7) __syncthreads();
    }

    // epilogue: concat-head layout oc[n][h*64 + d], d = lane (coalesced)
    #pragma unroll
    for (int c = 0; c < 4; ++c) {
        const int gi = i0 + 4 * w + c;
        oc[(long)(b * SS + gi) * DD + h * HSD + ln] = oA[c];
    }
}

// ---------------------------------------------------------------------------
// LayerNorm with fused split-K=2 reduction (round-5 version, unchanged).
// ---------------------------------------------------------------------------
__device__ __forceinline__ float blk_sum(float v, float* sb)
{
    #pragma unroll
    for (int m = 32; m >= 1; m >>= 1) v += __shfl_xor(v, m);
    if ((threadIdx.x & 63) == 0) sb[threadIdx.x >> 6] = v;
    __syncthreads();
    v = sb[0] + sb[1] + sb[2] + sb[3];
    __syncthreads();
    return v;
}

template<int NP>
__global__ __launch_bounds__(256)
void ln_fuse_kernel(const float* __restrict__ P, const float* __restrict__ bias,
                    const float* __restrict__ res,
                    const float* __restrict__ g, const float* __restrict__ bb,
                    float* __restrict__ out)
{
    __shared__ float sb[4];
    const int n = blockIdx.x;
    const int t = threadIdx.x;
    float v0 = P[(long)n * DD + t];
    float v1 = P[(long)n * DD + t + 256];
    #pragma unroll
    for (int p = 1; p < NP; ++p) {
        v0 += P[(long)p * NROWS * DD + (long)n * DD + t];
        v1 += P[(long)p * NROWS * DD + (long)n * DD + t + 256];
    }
    v0 += bias[t];       v1 += bias[t + 256];
    v0 += res[(long)n * DD + t];
    v1 += res[(long)n * DD + t + 256];

    float total = blk_sum(v0 + v1, sb);
    float mean = total * (1.0f / 512.0f);
    float d0 = v0 - mean, d1 = v1 - mean;
    float ss = blk_sum(d0 * d0 + d1 * d1, sb);
    float var = ss * (1.0f / 512.0f);
    float inv = 1.0f / sqrtf(var + EPS);
    out[(long)n * DD + t]       = d0 * inv * g[t]       + bb[t];
    out[(long)n * DD + t + 256] = d1 * inv * g[t + 256] + bb[t + 256];
}

// ---------------------------------------------------------------------------
extern "C" void kernel_launch(void* const* d_in, const int* in_sizes, int n_in,
                              void* d_out, int out_size, void* d_ws, size_t ws_size,
                              hipStream_t stream)
{
    const float* tokens = (const float*)d_in[0];
    const float* emb    = (const float*)d_in[1];
    const float* qkv_w  = (const float*)d_in[2];
    const float* qkv_b  = (const float*)d_in[3];
    const float* out_w  = (const float*)d_in[4];
    const float* out_b  = (const float*)d_in[5];
    const float* w1     = (const float*)d_in[6];
    const float* b1     = (const float*)d_in[7];
    const float* w2     = (const float*)d_in[8];
    const float* b2     = (const float*)d_in[9];
    const float* ln1_g  = (const float*)d_in[10];
    const float* ln1_b  = (const float*)d_in[11];
    const float* ln2_g  = (const float*)d_in[12];
    const float* ln2_b  = (const float*)d_in[13];
    float* out = (float*)d_out;

    float* ws  = (float*)d_ws;
    float* x   = ws;                          // [4096,512]
    float* y   = x  + (long)NROWS * DD;       // [4096,512]
    float* oc  = y  + (long)NROWS * DD;       // [4096,512]
    float* big = oc + (long)NROWS * DD;       // [4096,2048]
    // split-K=2 partial buffers (round-5 layout; zero extra workspace):
    //  - out-proj partials: big[0..2M), big[2M..4M)   (big free until FFN1)
    //  - FFN2 partials:     y[0..2M) and oc (contiguous after y)
    float* opP  = big;                        // 2 x [4096,512]
    float* ffP  = y;                          // slice 0; slice 1 = y + 2M = oc

    embed_kernel<<<NROWS, 256, 0, stream>>>(tokens, emb, x);

    for (int l = 0; l < LL; ++l) {
        const float* qw  = qkv_w + (long)l * HH * DD * 192;
        const float* qb  = qkv_b + (long)l * HH * 192;
        const float* ow  = out_w + (long)l * DD * DD;
        const float* ob  = out_b + (long)l * DD;
        const float* w1l = w1 + (long)l * DD * FFD;
        const float* b1l = b1 + (long)l * FFD;
        const float* w2l = w2 + (long)l * FFD * DD;
        const float* b2l = b2 + (long)l * DD;

        // QKV: [4096,512] @ per-head-remapped [512,1536] -> big (ldc=1536)
        gemm_t<64, false, true, true, false, false, 1><<<dim3(24, 32), 256, 0, stream>>>(
            x, qw, qb, nullptr, big, NROWS, 1536, DD, DD, 192, 1536);

        attn_kernel<<<dim3(SS / 16, HH, BB), 256, 0, stream>>>(big, oc);

        // out-proj, split-K=2 -> raw partials in big (free until FFN1)
        gemm_t<64, false, false, false, false, false, 2><<<dim3(8, 32, 2), 256, 0, stream>>>(
            oc, ow, nullptr, nullptr, opP, NROWS, DD, DD, DD, DD, DD);

        // ln1 fused: (p0+p1)+ob+x -> LN -> x
        ln_fuse_kernel<2><<<NROWS, 256, 0, stream>>>(
            opP, ob, x, ln1_g + (long)l * DD, ln1_b + (long)l * DD, x);

        // FFN1 + relu -> big
        gemm_t<128, false, false, true, true, false, 1><<<dim3(16, 32), 256, 0, stream>>>(
            x, w1l, b1l, nullptr, big, NROWS, FFD, DD, DD, FFD, FFD);

        // FFN2, split-K=2 -> raw partials in y/oc (both free here)
        gemm_t<64, false, false, false, false, false, 2><<<dim3(8, 32, 2), 256, 0, stream>>>(
            big, w2l, nullptr, nullptr, ffP, NROWS, DD, FFD, FFD, DD, DD);

        // ln2 fused: (p0+p1)+b2+x -> LN -> x
        ln_fuse_kernel<2><<<NROWS, 256, 0, stream>>>(
            ffP, b2l, x, ln2_g + (long)l * DD, ln2_b + (long)l * DD, x);
    }

    // final: out = x @ emb^T
    gemm_t<64, true, false, false, false, false, 1><<<dim3(16, 32), 256, 0, stream>>>(
        x, emb, nullptr, nullptr, out, NROWS, VV, DD, DD, DD, VV);
}